// Round 5
// baseline (2197.514 us; speedup 1.0000x reference)
//
#include <hip/hip_runtime.h>

// RNN on MI355X: h_{t+1} = tanh(table[X[:,t]] + h_t @ W_hh), T=256, B=1024, H=512.
// Round 5: r4 structure, but ALL MFMAs via builtins. r4's inline-asm MFMAs
// lacked compiler hazard handling (MFMA multi-pass WAR on SrcA: the next
// ds_read clobbered the A-frag mid-MFMA) -> absmax 1.137. Builtins get the
// hazard recognizer. AGPR residency still forced by one-time "+a" pin.
//  - 64 blocks x 256 thr (4 waves, 1 wave/EU -> 512-reg budget).
//  - Wave owns 128 cols = 8 frags x 16 k-sets. Sets 0..11 = 384 AGPRs
//    (pinned once); sets 12..15 in LDS (128KB, staged once).
//    ZERO per-step global W traffic.
//  - f16 single-term: predicted absmax ~0.003 (threshold 0.0534).

typedef __attribute__((ext_vector_type(4))) float f32x4;
typedef __attribute__((ext_vector_type(8))) _Float16 f16x8;

#define T_ 256
#define E_ 128
#define H_ 512
#define V_ 115

__device__ inline float tanh_fast(float x) {
  float e = __expf(-2.0f * fabsf(x));
  float t = (1.0f - e) / (1.0f + e);
  return copysignf(t, x);
}

// table[v][h] = b_h[h] + sum_e W_emb[v][e] * W_xh[e][h]   (115 x 512, f32)
__global__ void prep_table(const float* __restrict__ Wemb, const float* __restrict__ Wxh,
                           const float* __restrict__ bh, float* __restrict__ Txh) {
  int v = blockIdx.x;
  int h = threadIdx.x;
  float s = bh[h];
  const float* we = Wemb + v * E_;
#pragma unroll 8
  for (int e = 0; e < E_; ++e) s += we[e] * Wxh[e * H_ + h];
  Txh[v * H_ + h] = s;
}

// Wf layout (f16): frag (nb=n>>4, kc=k>>5) is a contiguous 1KB block of 64
// lanes x 16B; lane (lg*16+lm) holds col n=nb*16+lm, k=kc*32+lg*8..+8.
__global__ void prep_wf(const float* __restrict__ Whh, _Float16* __restrict__ Wf) {
  int idx = blockIdx.x * 256 + threadIdx.x;  // 512*512
  int k = idx >> 9, n = idx & 511;
  float w = Whh[k * H_ + n];
  int nb = n >> 4, lm = n & 15, kc = k >> 5, lg = (k >> 3) & 3, kk = k & 7;
  Wf[(((nb * 16 + kc) * 4 + lg) * 16 + lm) * 8 + kk] = (_Float16)w;
}

// resident W frag (f, set s) for wave with col-block base nb0
#define WG(f, s) (((const f16x8*)Wf)[(((nb0 + (f)) * 16 + (s)) << 6) + lane])

#define DECL8(s)                                                        \
  f16x8 W##s##_0 = WG(0, s), W##s##_1 = WG(1, s), W##s##_2 = WG(2, s),  \
        W##s##_3 = WG(3, s), W##s##_4 = WG(4, s), W##s##_5 = WG(5, s),  \
        W##s##_6 = WG(6, s), W##s##_7 = WG(7, s);

// One-time: force into AGPR class; blocks remat of the defining loads.
#define PIN8(s)                                                          \
  asm volatile("" : "+a"(W##s##_0), "+a"(W##s##_1), "+a"(W##s##_2),      \
                    "+a"(W##s##_3), "+a"(W##s##_4), "+a"(W##s##_5),      \
                    "+a"(W##s##_6), "+a"(W##s##_7));

#define MMB(ac, a8, wv) \
  ac = __builtin_amdgcn_mfma_f32_16x16x32_f16(a8, wv, ac, 0, 0, 0);

#define RSET(s) {                                                  \
  f16x8 a8 = *(const f16x8*)(Ah + (s) * 512 + lane * 8);           \
  MMB(acc0, a8, W##s##_0) MMB(acc1, a8, W##s##_1)                  \
  MMB(acc2, a8, W##s##_2) MMB(acc3, a8, W##s##_3)                  \
  MMB(acc4, a8, W##s##_4) MMB(acc5, a8, W##s##_5)                  \
  MMB(acc6, a8, W##s##_6) MMB(acc7, a8, W##s##_7) }

#define LSET(j) {                                                  \
  f16x8 a8 = *(const f16x8*)(Ah + (12 + (j)) * 512 + lane * 8);    \
  const f16x8* wp = (const f16x8*)WL + ((w * 32 + (j) * 8) << 6) + lane; \
  f16x8 q0 = wp[0 * 64], q1 = wp[1 * 64], q2 = wp[2 * 64], q3 = wp[3 * 64]; \
  f16x8 q4 = wp[4 * 64], q5 = wp[5 * 64], q6 = wp[6 * 64], q7 = wp[7 * 64]; \
  MMB(acc0, a8, q0) MMB(acc1, a8, q1) MMB(acc2, a8, q2) MMB(acc3, a8, q3)   \
  MMB(acc4, a8, q4) MMB(acc5, a8, q5) MMB(acc6, a8, q6) MMB(acc7, a8, q7) }

#define EPI(f) {                                                   \
  int n = w * 128 + (f) * 16 + lm;                                 \
  int bidx = (n >> 5) * 512 + ((n >> 3) & 3) * 128 + (n & 7);      \
  _Pragma("unroll")                                                \
  for (int r = 0; r < 4; ++r) {                                    \
    int m = lg * 4 + r;                                            \
    float hv = tanh_fast(acc##f[r] + xh[f][r]);                    \
    Ah[bidx + m * 8] = (_Float16)hv;                               \
    if (t == T_ - 1) Hfin[(r0 + m) * H_ + n] = hv;                 \
  } }

__global__ __launch_bounds__(256, 1) __attribute__((amdgpu_waves_per_eu(1, 1)))
void rnn_main(const int* __restrict__ X, const float* __restrict__ Txh,
              const _Float16* __restrict__ Wf, const float* __restrict__ Why,
              const float* __restrict__ by, float* __restrict__ Hfin,
              float* __restrict__ out) {
  __shared__ _Float16 Ah[16 * H_];        // 16 KB: h_t (f16, A-frag layout)
  __shared__ _Float16 WL[65536];          // 128 KB: W sets 12..15, all 4 waves
  __shared__ unsigned char sXb[16 * T_];  // 4 KB: X rows as bytes (vocab<256)

  const int tid = threadIdx.x;
  const int lane = tid & 63;
  const int w = tid >> 6;          // wave 0..3; owns cols [w*128, w*128+128)
  const int nb0 = w * 8;
  const int r0 = blockIdx.x * 16;
  const int lm = lane & 15;
  const int lg = lane >> 4;

  for (int i = tid; i < 16 * H_ / 2; i += 256) ((int*)Ah)[i] = 0;
  for (int i = tid; i < 16 * T_; i += 256)
    sXb[i] = (unsigned char)X[(r0 + (i >> 8)) * T_ + (i & 255)];
  // Stage W sets 12..15 for all waves into LDS (one time, 128 KB).
  for (int i = tid; i < 8192; i += 256) {
    int frag = i >> 6, ln = i & 63;
    int fw = frag >> 5, j = (frag >> 3) & 3, f = frag & 7;
    int nb = fw * 8 + f;
    ((f16x8*)WL)[(frag << 6) + ln] =
        ((const f16x8*)Wf)[((nb * 16 + 12 + j) << 6) + ln];
  }

  // Resident W: sets 0..11 -> 96 frags = 384 AGPRs, loaded once, pinned.
  DECL8(0) DECL8(1) DECL8(2) DECL8(3) DECL8(4) DECL8(5)
  DECL8(6) DECL8(7) DECL8(8) DECL8(9) DECL8(10) DECL8(11)
  PIN8(0) PIN8(1) PIN8(2) PIN8(3) PIN8(4) PIN8(5)
  PIN8(6) PIN8(7) PIN8(8) PIN8(9) PIN8(10) PIN8(11)

  __syncthreads();

  for (int t = 0; t < T_; ++t) {
    // xh gather (L2): issued up front, consumed in epilogue (fully hidden)
    float xh[8][4];
#pragma unroll
    for (int r = 0; r < 4; ++r) {
      int vx = sXb[(lg * 4 + r) * T_ + t];
      const float* tp = Txh + vx * H_ + w * 128 + lm;
#pragma unroll
      for (int f = 0; f < 8; ++f) xh[f][r] = tp[f * 16];
    }

    f32x4 acc0 = {0.f,0.f,0.f,0.f}, acc1 = {0.f,0.f,0.f,0.f};
    f32x4 acc2 = {0.f,0.f,0.f,0.f}, acc3 = {0.f,0.f,0.f,0.f};
    f32x4 acc4 = {0.f,0.f,0.f,0.f}, acc5 = {0.f,0.f,0.f,0.f};
    f32x4 acc6 = {0.f,0.f,0.f,0.f}, acc7 = {0.f,0.f,0.f,0.f};

    RSET(0) RSET(1) RSET(2) RSET(3) RSET(4) RSET(5)
    RSET(6) RSET(7) RSET(8) RSET(9) RSET(10) RSET(11)
    LSET(0) LSET(1) LSET(2) LSET(3)

    __syncthreads();  // all A-reads done; safe to overwrite Ah

    EPI(0) EPI(1) EPI(2) EPI(3) EPI(4) EPI(5) EPI(6) EPI(7)

    __syncthreads();  // new h visible for next step
  }

  __syncthreads();

  // logits = h_T @ W_hy + b_y for this block's 16 rows
  for (int idx = tid; idx < 16 * V_; idx += 256) {
    int m = idx / V_, v = idx - m * V_;
    const float* hp = Hfin + (r0 + m) * H_;
    float s = by[v];
#pragma unroll 8
    for (int k = 0; k < H_; ++k) s += hp[k] * Why[k * V_ + v];
    out[(r0 + m) * V_ + v] = s;
  }
}

extern "C" void kernel_launch(void* const* d_in, const int* in_sizes, int n_in,
                              void* d_out, int out_size, void* d_ws, size_t ws_size,
                              hipStream_t stream) {
  const int* X = (const int*)d_in[0];         // [1024,256] int32
  const float* Wemb = (const float*)d_in[1];  // [115,128]
  const float* Wxh = (const float*)d_in[2];   // [128,512]
  const float* Whh = (const float*)d_in[3];   // [512,512]
  const float* bh = (const float*)d_in[4];    // [512]
  const float* Why = (const float*)d_in[5];   // [512,115]
  const float* by = (const float*)d_in[6];    // [115]
  float* out = (float*)d_out;                 // [1024,115]

  char* ws = (char*)d_ws;
  float* Txh = (float*)ws;                        // 235,520 B
  _Float16* Wf = (_Float16*)(ws + 256 * 1024);    // 512 KB
  float* Hfin = (float*)(ws + 1024 * 1024);       // 2 MB

  prep_table<<<dim3(V_), dim3(H_), 0, stream>>>(Wemb, Wxh, bh, Txh);
  prep_wf<<<dim3(1024), dim3(256), 0, stream>>>(Whh, Wf);
  rnn_main<<<dim3(64), dim3(256), 0, stream>>>(X, Txh, Wf, Why, by, Hfin, out);
}

// Round 6
// 1400.548 us; speedup vs baseline: 1.5690x; 1.5690x over previous
//
#include <hip/hip_runtime.h>

// RNN on MI355X: h_{t+1} = tanh(table[X[:,t]] + h_t @ W_hh), T=256, B=1024, H=512.
// Round 6: feasible full-residency split. r5 asked 384 AGPRs but the per-wave
// class caps are 256 arch + 256 acc (r5 tell: VGPR_Count=256 + 9MB scratch).
//  - 64 blocks x 256 thr (4 waves, 1 wave/SIMD -> 512-reg unified budget).
//  - Wave owns 128 cols = 8 frags x 16 k-sets (32 regs/set):
//      sets 0..7  -> AGPR   (256 = class cap), pinned "+a"
//      sets 8..11 -> VGPR   (128 arch), pinned "+v"
//      sets 12..15-> LDS    (128 KB, staged once)
//    ZERO per-step global W traffic, zero scratch if RA cooperates
//    (diagnostic: WRITE_SIZE ~3 MB means success).
//  - f16 single-term MFMA via builtins (hazards handled): absmax ~0.008.

typedef __attribute__((ext_vector_type(4))) float f32x4;
typedef __attribute__((ext_vector_type(8))) _Float16 f16x8;

#define T_ 256
#define E_ 128
#define H_ 512
#define V_ 115

__device__ inline float tanh_fast(float x) {
  float e = __expf(-2.0f * fabsf(x));
  float t = (1.0f - e) / (1.0f + e);
  return copysignf(t, x);
}

// table[v][h] = b_h[h] + sum_e W_emb[v][e] * W_xh[e][h]   (115 x 512, f32)
__global__ void prep_table(const float* __restrict__ Wemb, const float* __restrict__ Wxh,
                           const float* __restrict__ bh, float* __restrict__ Txh) {
  int v = blockIdx.x;
  int h = threadIdx.x;
  float s = bh[h];
  const float* we = Wemb + v * E_;
#pragma unroll 8
  for (int e = 0; e < E_; ++e) s += we[e] * Wxh[e * H_ + h];
  Txh[v * H_ + h] = s;
}

// Wf layout (f16): frag (nb=n>>4, kc=k>>5) is a contiguous 1KB block of 64
// lanes x 16B; lane (lg*16+lm) holds col n=nb*16+lm, k=kc*32+lg*8..+8.
__global__ void prep_wf(const float* __restrict__ Whh, _Float16* __restrict__ Wf) {
  int idx = blockIdx.x * 256 + threadIdx.x;  // 512*512
  int k = idx >> 9, n = idx & 511;
  float w = Whh[k * H_ + n];
  int nb = n >> 4, lm = n & 15, kc = k >> 5, lg = (k >> 3) & 3, kk = k & 7;
  Wf[(((nb * 16 + kc) * 4 + lg) * 16 + lm) * 8 + kk] = (_Float16)w;
}

// resident W frag (f, set s) for wave with col-block base nb0
#define WG(f, s) (((const f16x8*)Wf)[(((nb0 + (f)) * 16 + (s)) << 6) + lane])

#define DECL8(s)                                                        \
  f16x8 W##s##_0 = WG(0, s), W##s##_1 = WG(1, s), W##s##_2 = WG(2, s),  \
        W##s##_3 = WG(3, s), W##s##_4 = WG(4, s), W##s##_5 = WG(5, s),  \
        W##s##_6 = WG(6, s), W##s##_7 = WG(7, s);

// One-time class pins (block remat of the defining loads; choose reg class).
#define PIN8A(s)                                                         \
  asm volatile("" : "+a"(W##s##_0), "+a"(W##s##_1), "+a"(W##s##_2),      \
                    "+a"(W##s##_3), "+a"(W##s##_4), "+a"(W##s##_5),      \
                    "+a"(W##s##_6), "+a"(W##s##_7));
#define PIN8V(s)                                                         \
  asm volatile("" : "+v"(W##s##_0), "+v"(W##s##_1), "+v"(W##s##_2),      \
                    "+v"(W##s##_3), "+v"(W##s##_4), "+v"(W##s##_5),      \
                    "+v"(W##s##_6), "+v"(W##s##_7));

#define MMB(ac, a8, wv) \
  ac = __builtin_amdgcn_mfma_f32_16x16x32_f16(a8, wv, ac, 0, 0, 0);

#define RSET(s) {                                                  \
  f16x8 a8 = *(const f16x8*)(Ah + (s) * 512 + lane * 8);           \
  MMB(acc0, a8, W##s##_0) MMB(acc1, a8, W##s##_1)                  \
  MMB(acc2, a8, W##s##_2) MMB(acc3, a8, W##s##_3)                  \
  MMB(acc4, a8, W##s##_4) MMB(acc5, a8, W##s##_5)                  \
  MMB(acc6, a8, W##s##_6) MMB(acc7, a8, W##s##_7) }

#define LSET(j) {                                                  \
  f16x8 a8 = *(const f16x8*)(Ah + (12 + (j)) * 512 + lane * 8);    \
  const f16x8* wp = (const f16x8*)WL + ((w * 32 + (j) * 8) << 6) + lane; \
  f16x8 q0 = wp[0 * 64], q1 = wp[1 * 64], q2 = wp[2 * 64], q3 = wp[3 * 64]; \
  MMB(acc0, a8, q0) MMB(acc1, a8, q1) MMB(acc2, a8, q2) MMB(acc3, a8, q3)   \
  f16x8 q4 = wp[4 * 64], q5 = wp[5 * 64], q6 = wp[6 * 64], q7 = wp[7 * 64]; \
  MMB(acc4, a8, q4) MMB(acc5, a8, q5) MMB(acc6, a8, q6) MMB(acc7, a8, q7) }

#define EPI(f) {                                                   \
  int n = w * 128 + (f) * 16 + lm;                                 \
  int bidx = (n >> 5) * 512 + ((n >> 3) & 3) * 128 + (n & 7);      \
  _Pragma("unroll")                                                \
  for (int r = 0; r < 4; ++r) {                                    \
    int m = lg * 4 + r;                                            \
    float hv = tanh_fast(acc##f[r] + xh[f][r]);                    \
    Ah[bidx + m * 8] = (_Float16)hv;                               \
    if (t == T_ - 1) Hfin[(r0 + m) * H_ + n] = hv;                 \
  } }

__global__ __launch_bounds__(256, 1) __attribute__((amdgpu_waves_per_eu(1, 1)))
void rnn_main(const int* __restrict__ X, const float* __restrict__ Txh,
              const _Float16* __restrict__ Wf, const float* __restrict__ Why,
              const float* __restrict__ by, float* __restrict__ Hfin,
              float* __restrict__ out) {
  __shared__ _Float16 Ah[16 * H_];        // 16 KB: h_t (f16, A-frag layout)
  __shared__ _Float16 WL[65536];          // 128 KB: W sets 12..15, all 4 waves
  __shared__ unsigned char sXb[16 * T_];  // 4 KB: X rows as bytes (vocab<256)

  const int tid = threadIdx.x;
  const int lane = tid & 63;
  const int w = tid >> 6;          // wave 0..3; owns cols [w*128, w*128+128)
  const int nb0 = w * 8;
  const int r0 = blockIdx.x * 16;
  const int lm = lane & 15;
  const int lg = lane >> 4;

  for (int i = tid; i < 16 * H_ / 2; i += 256) ((int*)Ah)[i] = 0;
  for (int i = tid; i < 16 * T_; i += 256)
    sXb[i] = (unsigned char)X[(r0 + (i >> 8)) * T_ + (i & 255)];
  // Stage W sets 12..15 for all waves into LDS (one time, 128 KB).
  for (int i = tid; i < 8192; i += 256) {
    int frag = i >> 6, ln = i & 63;
    int fw = frag >> 5, j = (frag >> 3) & 3, f = frag & 7;
    int nb = fw * 8 + f;
    ((f16x8*)WL)[(frag << 6) + ln] =
        ((const f16x8*)Wf)[((nb * 16 + 12 + j) << 6) + ln];
  }

  // Resident W: sets 0..7 -> AGPR (256 = class cap); 8..11 -> arch VGPR (128).
  DECL8(0) DECL8(1) DECL8(2) DECL8(3) DECL8(4) DECL8(5)
  DECL8(6) DECL8(7) DECL8(8) DECL8(9) DECL8(10) DECL8(11)
  PIN8A(0) PIN8A(1) PIN8A(2) PIN8A(3) PIN8A(4) PIN8A(5) PIN8A(6) PIN8A(7)
  PIN8V(8) PIN8V(9) PIN8V(10) PIN8V(11)

  __syncthreads();

  for (int t = 0; t < T_; ++t) {
    // xh gather (L2): issued up front, consumed in epilogue (fully hidden)
    float xh[8][4];
#pragma unroll
    for (int r = 0; r < 4; ++r) {
      int vx = sXb[(lg * 4 + r) * T_ + t];
      const float* tp = Txh + vx * H_ + w * 128 + lm;
#pragma unroll
      for (int f = 0; f < 8; ++f) xh[f][r] = tp[f * 16];
    }

    f32x4 acc0 = {0.f,0.f,0.f,0.f}, acc1 = {0.f,0.f,0.f,0.f};
    f32x4 acc2 = {0.f,0.f,0.f,0.f}, acc3 = {0.f,0.f,0.f,0.f};
    f32x4 acc4 = {0.f,0.f,0.f,0.f}, acc5 = {0.f,0.f,0.f,0.f};
    f32x4 acc6 = {0.f,0.f,0.f,0.f}, acc7 = {0.f,0.f,0.f,0.f};

    RSET(0) RSET(1) RSET(2) RSET(3) RSET(4) RSET(5)
    RSET(6) RSET(7) RSET(8) RSET(9) RSET(10) RSET(11)
    LSET(0) LSET(1) LSET(2) LSET(3)

    __syncthreads();  // all A-reads done; safe to overwrite Ah

    EPI(0) EPI(1) EPI(2) EPI(3) EPI(4) EPI(5) EPI(6) EPI(7)

    __syncthreads();  // new h visible for next step
  }

  __syncthreads();

  // logits = h_T @ W_hy + b_y for this block's 16 rows
  for (int idx = tid; idx < 16 * V_; idx += 256) {
    int m = idx / V_, v = idx - m * V_;
    const float* hp = Hfin + (r0 + m) * H_;
    float s = by[v];
#pragma unroll 8
    for (int k = 0; k < H_; ++k) s += hp[k] * Why[k * V_ + v];
    out[(r0 + m) * V_ + v] = s;
  }
}

extern "C" void kernel_launch(void* const* d_in, const int* in_sizes, int n_in,
                              void* d_out, int out_size, void* d_ws, size_t ws_size,
                              hipStream_t stream) {
  const int* X = (const int*)d_in[0];         // [1024,256] int32
  const float* Wemb = (const float*)d_in[1];  // [115,128]
  const float* Wxh = (const float*)d_in[2];   // [128,512]
  const float* Whh = (const float*)d_in[3];   // [512,512]
  const float* bh = (const float*)d_in[4];    // [512]
  const float* Why = (const float*)d_in[5];   // [512,115]
  const float* by = (const float*)d_in[6];    // [115]
  float* out = (float*)d_out;                 // [1024,115]

  char* ws = (char*)d_ws;
  float* Txh = (float*)ws;                        // 235,520 B
  _Float16* Wf = (_Float16*)(ws + 256 * 1024);    // 512 KB
  float* Hfin = (float*)(ws + 1024 * 1024);       // 2 MB

  prep_table<<<dim3(V_), dim3(H_), 0, stream>>>(Wemb, Wxh, bh, Txh);
  prep_wf<<<dim3(1024), dim3(256), 0, stream>>>(Whh, Wf);
  rnn_main<<<dim3(64), dim3(256), 0, stream>>>(X, Txh, Wf, Why, by, Hfin, out);
}